// Round 1
// baseline (738.275 us; speedup 1.0000x reference)
//
#include <hip/hip_runtime.h>
#include <math.h>

#define NN 50000
#define NE 800000
#define CIN0 64
#define COUT 32
#define KK 10
#define HXW 352            // K*OUT + OUT  (h columns 0..319, root columns 320..351)
#define EPSV 1e-15f

// ---------------- degree ----------------
__global__ void deg_kernel(const int* __restrict__ ei, float* __restrict__ deg) {
    int e = blockIdx.x * 256 + threadIdx.x;
    if (e >= NE) return;
    atomicAdd(deg + ei[NE + e], 1.0f);
}

__global__ void invdeg_kernel(float* __restrict__ deg) {
    int n = blockIdx.x * 256 + threadIdx.x;
    if (n >= NN) return;
    deg[n] = 1.0f / fmaxf(deg[n], 1.0f);
}

// ---------------- hx = x @ [g | root]  ([N,cin] x [cin,352]) ----------------
template <int CIN>
__global__ __launch_bounds__(384) void gemm_hx(const float* __restrict__ x,
                                               const float* __restrict__ g,
                                               const float* __restrict__ root,
                                               float* __restrict__ hx) {
    __shared__ float xs[16 * CIN];
    const int n0 = blockIdx.x * 16;                 // N = 50000 = 16*3125 exact
    const int tid = threadIdx.x;
    for (int idx = tid; idx < 16 * CIN; idx += 384)
        xs[idx] = x[(size_t)n0 * CIN + idx];
    __syncthreads();
    const int j = tid;
    if (j < HXW) {
        float acc[16];
#pragma unroll
        for (int i = 0; i < 16; i++) acc[i] = 0.0f;
        const bool isg = (j < KK * COUT);
        const float* w = isg ? (g + j) : (root + (j - KK * COUT));
        const int wstride = isg ? (KK * COUT) : COUT;
        for (int c = 0; c < CIN; c++) {
            float wv = w[(size_t)c * wstride];
#pragma unroll
            for (int i = 0; i < 16; i++)
                acc[i] = fmaf(xs[i * CIN + c], wv, acc[i]);
        }
#pragma unroll
        for (int i = 0; i < 16; i++)
            hx[(size_t)(n0 + i) * HXW + j] = acc[i];
    }
}

// ---------------- gaussian edge weights: gw[e,k] ----------------
__global__ void gauss_kernel(const float* __restrict__ ea,
                             const float* __restrict__ mu,
                             const float* __restrict__ sigma,
                             float* __restrict__ gw) {
    int e = blockIdx.x * 256 + threadIdx.x;
    if (e >= NE) return;
    float a0 = ea[2 * e], a1 = ea[2 * e + 1];
    float out[KK];
#pragma unroll
    for (int k = 0; k < KK; k++) {
        float s0 = sigma[2 * k], s1 = sigma[2 * k + 1];
        float i0 = 1.0f / (EPSV + s0 * s0);
        float i1 = 1.0f / (EPSV + s1 * s1);
        float d0 = a0 - mu[2 * k];
        float d1 = a1 - mu[2 * k + 1];
        out[k] = expf(-0.5f * (d0 * d0 * i0 + d1 * d1 * i1));
    }
#pragma unroll
    for (int k = 0; k < KK; k++) gw[(size_t)e * KK + k] = out[k];
}

// ---------------- edge-parallel scatter: agg[dst,o] += sum_k gw[e,k]*h[src,k,o] ----------------
__global__ __launch_bounds__(256) void scatter_kernel(const float* __restrict__ hx,
                                                      const float* __restrict__ gw,
                                                      const int* __restrict__ ei,
                                                      float* __restrict__ agg) {
    long long t = (long long)blockIdx.x * 256 + threadIdx.x;
    int e = (int)(t >> 5);
    int o = (int)(t & 31);
    if (e >= NE) return;
    int src = ei[e];
    int dst = ei[NE + e];
    const float* hrow = hx + (size_t)src * HXW + o;
    float acc = 0.0f;
#pragma unroll
    for (int k = 0; k < KK; k++)
        acc = fmaf(gw[(size_t)e * KK + k], hrow[(size_t)k * COUT], acc);
    atomicAdd(agg + (size_t)dst * COUT + o, acc);
}

// ---------------- finalize: out = elu(agg*invdeg + x@root + b) ----------------
__global__ void finalize_kernel(const float* __restrict__ agg,
                                const float* __restrict__ hx,
                                const float* __restrict__ invdeg,
                                const float* __restrict__ b,
                                float* __restrict__ out) {
    int t = blockIdx.x * 256 + threadIdx.x;
    if (t >= NN * COUT) return;
    int n = t >> 5, o = t & 31;
    float v = agg[t] * invdeg[n] + hx[(size_t)n * HXW + KK * COUT + o] + b[o];
    out[t] = (v > 0.0f) ? v : (expf(v) - 1.0f);
}

extern "C" void kernel_launch(void* const* d_in, const int* in_sizes, int n_in,
                              void* d_out, int out_size, void* d_ws, size_t ws_size,
                              hipStream_t stream) {
    const float* graph = (const float*)d_in[0];
    const int* ei = (const int*)d_in[1];
    const float* ea = (const float*)d_in[2];
    // per-layer params start at index 3: g, mu, sigma, root, b
    const float* G[3];
    const float* MU[3];
    const float* SG[3];
    const float* RT[3];
    const float* BB[3];
    for (int l = 0; l < 3; l++) {
        G[l] = (const float*)d_in[3 + 5 * l + 0];
        MU[l] = (const float*)d_in[3 + 5 * l + 1];
        SG[l] = (const float*)d_in[3 + 5 * l + 2];
        RT[l] = (const float*)d_in[3 + 5 * l + 3];
        BB[l] = (const float*)d_in[3 + 5 * l + 4];
    }
    float* out = (float*)d_out;

    // workspace layout (floats)
    float* hx = (float*)d_ws;                       // N*352     = 17.6M
    float* gw = hx + (size_t)NN * HXW;              // E*10      = 8.0M
    float* agg = gw + (size_t)NE * KK;              // N*32      = 1.6M
    float* deg = agg + (size_t)NN * COUT;           // N         = 0.05M

    // degree (once)
    hipMemsetAsync(deg, 0, NN * sizeof(float), stream);
    deg_kernel<<<(NE + 255) / 256, 256, 0, stream>>>(ei, deg);
    invdeg_kernel<<<(NN + 255) / 256, 256, 0, stream>>>(deg);

    for (int l = 0; l < 3; l++) {
        const float* x = (l == 0) ? graph : (out + (size_t)(l - 1) * NN * COUT);
        if (l == 0)
            gemm_hx<CIN0><<<NN / 16, 384, 0, stream>>>(x, G[l], RT[l], hx);
        else
            gemm_hx<COUT><<<NN / 16, 384, 0, stream>>>(x, G[l], RT[l], hx);
        gauss_kernel<<<(NE + 255) / 256, 256, 0, stream>>>(ea, MU[l], SG[l], gw);
        hipMemsetAsync(agg, 0, (size_t)NN * COUT * sizeof(float), stream);
        scatter_kernel<<<(int)(((long long)NE * 32 + 255) / 256), 256, 0, stream>>>(hx, gw, ei, agg);
        finalize_kernel<<<(NN * COUT + 255) / 256, 256, 0, stream>>>(
            agg, hx, deg, BB[l], out + (size_t)l * NN * COUT);
    }
}

// Round 3
// 634.291 us; speedup vs baseline: 1.1639x; 1.1639x over previous
//
#include <hip/hip_runtime.h>
#include <math.h>

#define NN 50000
#define NE 800000
#define COUT 32
#define KK 10
#define HXW 352            // K*OUT + OUT  (h columns 0..319, root columns 320..351)
#define GWP 12             // gw row padded to 12 floats (48 B, 16B-aligned)
#define EPSV 1e-15f

// ================= CSR build (once per call) =================

__global__ void count_deg(const int* __restrict__ ei, int* __restrict__ srcdeg,
                          int* __restrict__ dstdeg) {
    int e = blockIdx.x * 256 + threadIdx.x;
    if (e >= NE) return;
    atomicAdd(srcdeg + ei[e], 1);
    atomicAdd(dstdeg + ei[NE + e], 1);
}

// exclusive scan of srcdeg[0..NN) -> rowptr, cursor ; rowptr[NN]=NE. single block 1024.
__global__ __launch_bounds__(1024) void scan_kernel(const int* __restrict__ srcdeg,
                                                    int* __restrict__ rowptr,
                                                    int* __restrict__ cursor) {
    __shared__ int wsum[16];
    __shared__ int wpre[16];
    __shared__ int tot;
    __shared__ int carry;
    const int tid = threadIdx.x;
    const int wave = tid >> 6, lane = tid & 63;
    if (tid == 0) carry = 0;
    __syncthreads();
    for (int base = 0; base < NN; base += 1024) {
        int i = base + tid;
        int v = (i < NN) ? srcdeg[i] : 0;
        int incl = v;
#pragma unroll
        for (int off = 1; off < 64; off <<= 1) {
            int t = __shfl_up(incl, off);
            if (lane >= off) incl += t;
        }
        if (lane == 63) wsum[wave] = incl;
        __syncthreads();                       // wsum ready (also orders prev carry update)
        if (tid == 0) {
            int run = 0;
#pragma unroll
            for (int w = 0; w < 16; w++) { wpre[w] = run; run += wsum[w]; }
            tot = run;
        }
        __syncthreads();                       // wpre/tot ready
        if (i < NN) {
            int excl = carry + wpre[wave] + incl - v;
            rowptr[i] = excl;
            cursor[i] = excl;
        }
        __syncthreads();                       // everyone done reading carry
        if (tid == 0) carry += tot;
    }
    if (tid == 0) rowptr[NN] = NE;
}

__global__ void fill_csr(const int* __restrict__ ei, const float* __restrict__ ea,
                         int* __restrict__ cursor, int* __restrict__ coldst,
                         float* __restrict__ eaperm) {
    int e = blockIdx.x * 256 + threadIdx.x;
    if (e >= NE) return;
    int src = ei[e], dst = ei[NE + e];
    int slot = atomicAdd(cursor + src, 1);
    coldst[slot] = dst;
    float2 a = ((const float2*)ea)[e];
    ((float2*)eaperm)[slot] = a;
}

__global__ void invdeg_kernel(const int* __restrict__ dstdeg, float* __restrict__ invdeg) {
    int n = blockIdx.x * 256 + threadIdx.x;
    if (n >= NN) return;
    invdeg[n] = 1.0f / fmaxf((float)dstdeg[n], 1.0f);
}

// ================= per-layer kernels =================

// hx = x @ [g | root]  ([N,cin] x [cin,352]) ; 32 nodes/block, transposed LDS tile
template <int CIN>
__global__ __launch_bounds__(384) void gemm_hx(const float* __restrict__ x,
                                               const float* __restrict__ g,
                                               const float* __restrict__ root,
                                               float* __restrict__ hx) {
    __shared__ float xs[CIN][36];              // padded: 16B-aligned rows, conflict-lite writes
    const int n0 = blockIdx.x * 32;
    const int tid = threadIdx.x;
    for (int idx = tid; idx < 32 * CIN; idx += 384) {
        int i = idx / CIN, c = idx % CIN;      // coalesced read over x row
        int n = n0 + i;
        xs[c][i] = (n < NN) ? x[(size_t)n * CIN + c] : 0.0f;
    }
    __syncthreads();
    const int j = tid;
    if (j < HXW) {
        const bool isg = (j < KK * COUT);
        const float* w = isg ? (g + j) : (root + (j - KK * COUT));
        const int ws = isg ? (KK * COUT) : COUT;
        float acc[32];
#pragma unroll
        for (int i = 0; i < 32; i++) acc[i] = 0.0f;
        for (int c = 0; c < CIN; c++) {
            float wv = w[(size_t)c * ws];
            const float4* xr = (const float4*)&xs[c][0];
#pragma unroll
            for (int q = 0; q < 8; q++) {
                float4 v = xr[q];
                acc[4 * q + 0] = fmaf(v.x, wv, acc[4 * q + 0]);
                acc[4 * q + 1] = fmaf(v.y, wv, acc[4 * q + 1]);
                acc[4 * q + 2] = fmaf(v.z, wv, acc[4 * q + 2]);
                acc[4 * q + 3] = fmaf(v.w, wv, acc[4 * q + 3]);
            }
        }
#pragma unroll
        for (int i = 0; i < 32; i++) {
            int n = n0 + i;
            if (n < NN) hx[(size_t)n * HXW + j] = acc[i];
        }
    }
}

// gaussian edge weights in CSR slot order: gw[slot][0..9], padded to 12
__global__ void gauss_csr(const float* __restrict__ eaperm,
                          const float* __restrict__ mu,
                          const float* __restrict__ sigma,
                          float* __restrict__ gw) {
    int s = blockIdx.x * 256 + threadIdx.x;
    if (s >= NE) return;
    float2 a = ((const float2*)eaperm)[s];
    float o[12];
#pragma unroll
    for (int k = 0; k < KK; k++) {
        float s0 = sigma[2 * k], s1 = sigma[2 * k + 1];
        float i0 = 1.0f / (EPSV + s0 * s0);
        float i1 = 1.0f / (EPSV + s1 * s1);
        float d0 = a.x - mu[2 * k];
        float d1 = a.y - mu[2 * k + 1];
        o[k] = expf(-0.5f * (d0 * d0 * i0 + d1 * d1 * i1));
    }
    o[10] = 0.0f; o[11] = 0.0f;
    float4* p = (float4*)(gw + (size_t)s * GWP);
    p[0] = make_float4(o[0], o[1], o[2], o[3]);
    p[1] = make_float4(o[4], o[5], o[6], o[7]);
    p[2] = make_float4(o[8], o[9], o[10], o[11]);
}

// src-CSR scatter: wave per src node; h-row loaded once; 2 edges / wave-iter
__global__ __launch_bounds__(256) void scatter_src(const float* __restrict__ hx,
                                                   const float* __restrict__ gw,
                                                   const int* __restrict__ rowptr,
                                                   const int* __restrict__ coldst,
                                                   float* __restrict__ agg) {
    const int tid = threadIdx.x;
    const int wave = tid >> 6, lane = tid & 63;
    const int o = lane & 31, h = lane >> 5;
    const int nwaves = gridDim.x * 4;
    for (int n = blockIdx.x * 4 + wave; n < NN; n += nwaves) {
        const int s0 = rowptr[n], s1 = rowptr[n + 1];
        if (s0 == s1) continue;
        float hreg[KK];
#pragma unroll
        for (int k = 0; k < KK; k++)
            hreg[k] = hx[(size_t)n * HXW + 32 * k + o];
        for (int s = s0 + h; s < s1; s += 2) {
            int dst = coldst[s];
            const float4* gp = (const float4*)(gw + (size_t)s * GWP);
            float4 w0 = gp[0], w1 = gp[1], w2 = gp[2];
            float acc = w0.x * hreg[0] + w0.y * hreg[1] + w0.z * hreg[2] + w0.w * hreg[3]
                      + w1.x * hreg[4] + w1.y * hreg[5] + w1.z * hreg[6] + w1.w * hreg[7]
                      + w2.x * hreg[8] + w2.y * hreg[9];
            atomicAdd(agg + (size_t)dst * COUT + o, acc);
        }
    }
}

// out = elu(agg*invdeg + root-term + b)
__global__ void finalize_kernel(const float* __restrict__ agg,
                                const float* __restrict__ hx,
                                const float* __restrict__ invdeg,
                                const float* __restrict__ b,
                                float* __restrict__ out) {
    int t = blockIdx.x * 256 + threadIdx.x;
    if (t >= NN * COUT) return;
    int n = t >> 5, o = t & 31;
    float v = agg[t] * invdeg[n] + hx[(size_t)n * HXW + KK * COUT + o] + b[o];
    out[t] = (v > 0.0f) ? v : (expf(v) - 1.0f);
}

extern "C" void kernel_launch(void* const* d_in, const int* in_sizes, int n_in,
                              void* d_out, int out_size, void* d_ws, size_t ws_size,
                              hipStream_t stream) {
    const float* graph = (const float*)d_in[0];
    const int* ei = (const int*)d_in[1];
    const float* ea = (const float*)d_in[2];
    const float *G[3], *MU[3], *SG[3], *RT[3], *BB[3];
    for (int l = 0; l < 3; l++) {
        G[l]  = (const float*)d_in[3 + 5 * l + 0];
        MU[l] = (const float*)d_in[3 + 5 * l + 1];
        SG[l] = (const float*)d_in[3 + 5 * l + 2];
        RT[l] = (const float*)d_in[3 + 5 * l + 3];
        BB[l] = (const float*)d_in[3 + 5 * l + 4];
    }
    float* out = (float*)d_out;

    // ---- workspace layout ----
    float* hx     = (float*)d_ws;                          // NN*352   = 17.6M f
    float* gw     = hx + (size_t)NN * HXW;                 // NE*12    = 9.6M f  (16B aligned)
    float* agg    = gw + (size_t)NE * GWP;                 // NN*32    = 1.6M f
    float* invdeg = agg + (size_t)NN * COUT;               // NN
    float* eaperm = invdeg + NN;                           // NE*2     (8B aligned)
    int* rowptr   = (int*)(eaperm + (size_t)NE * 2);       // NN+1
    int* cursor   = rowptr + (NN + 1);                     // NN
    int* srcdeg   = cursor + NN;                           // NN
    int* dstdeg   = srcdeg + NN;                           // NN
    int* coldst   = dstdeg + NN;                           // NE

    // ---- CSR build (once) ----
    hipMemsetAsync(srcdeg, 0, NN * sizeof(int), stream);
    hipMemsetAsync(dstdeg, 0, NN * sizeof(int), stream);
    count_deg<<<(NE + 255) / 256, 256, 0, stream>>>(ei, srcdeg, dstdeg);
    scan_kernel<<<1, 1024, 0, stream>>>(srcdeg, rowptr, cursor);
    fill_csr<<<(NE + 255) / 256, 256, 0, stream>>>(ei, ea, cursor, coldst, eaperm);
    invdeg_kernel<<<(NN + 255) / 256, 256, 0, stream>>>(dstdeg, invdeg);

    for (int l = 0; l < 3; l++) {
        const float* x = (l == 0) ? graph : (out + (size_t)(l - 1) * NN * COUT);
        if (l == 0)
            gemm_hx<64><<<(NN + 31) / 32, 384, 0, stream>>>(x, G[l], RT[l], hx);
        else
            gemm_hx<32><<<(NN + 31) / 32, 384, 0, stream>>>(x, G[l], RT[l], hx);
        gauss_csr<<<(NE + 255) / 256, 256, 0, stream>>>(eaperm, MU[l], SG[l], gw);
        hipMemsetAsync(agg, 0, (size_t)NN * COUT * sizeof(float), stream);
        scatter_src<<<2048, 256, 0, stream>>>(hx, gw, rowptr, coldst, agg);
        finalize_kernel<<<(NN * COUT + 255) / 256, 256, 0, stream>>>(
            agg, hx, invdeg, BB[l], out + (size_t)l * NN * COUT);
    }
}